// Round 3
// baseline (473.205 us; speedup 1.0000x reference)
//
#include <hip/hip_runtime.h>

#define BATCH 128
#define NBOX 8732
#define NC 21
#define M (BATCH * NBOX)          // 1,117,696
#define RPB 128                   // rows per block in k_elem
#define NBLK (M / RPB)            // 8732 blocks
#define CLIP_MAX 16.118095651f    // -log(1e-7)

struct Ctl {
  float num_pos[BATCH];           // per-batch positive counts
  float pos_conf_sum, pos_loc_sum;
  float s_gt;                     // conf_loss sum strictly above threshold (bins)
  float s_eq;                     // conf_loss sum of bit-exact ties
  float denom;                    // sum num_pos_c
  unsigned int k_rem;             // remaining rank within current radix bin
  unsigned int prefix;            // accumulated threshold bits
  unsigned int n_eq;              // tie count at threshold
  unsigned int done;
  unsigned int pad[7];
  unsigned int hist[2048];
  float        hsum[2048];
};

// ---------------------------------------------------------------------------
// Pass 1: fused elementwise. Coalesced float4 staging; y_true is scatter-
// decoded during staging (loc/pos stored, onehot -> label int) so LDS/row is
// ~110 B instead of 188 B -> ~20 waves/CU instead of 8.
// ---------------------------------------------------------------------------
__global__ __launch_bounds__(RPB) void k_elem(
    const float* __restrict__ yt, const float* __restrict__ lp,
    const float* __restrict__ cp, float* __restrict__ MC,
    float* __restrict__ CL, Ctl* __restrict__ ctl) {
  __shared__ float  s_cp[RPB * NC];   // 10752 B, stride-21 reads: conflict-free
  __shared__ float4 s_loc[RPB];       // 2048 B
  __shared__ float  s_pos[RPB];       // 512 B
  __shared__ int    s_lab[RPB];       // 512 B (exactly one writer per row)
  __shared__ float  sred[8];          // ~13.9 KB total

  const int tid = threadIdx.x;
  const int r0 = blockIdx.x * RPB;

  // conf_pred chunk: 128*21*4 B (10752 % 16 == 0 -> aligned float4)
  {
    const float4* gc = (const float4*)(cp + (size_t)r0 * NC);
    float4* sc = (float4*)s_cp;
    for (int i = tid; i < RPB * NC / 4; i += RPB) sc[i] = gc[i];
  }
  // y_true chunk: 128*26*4 B (13312 % 16 == 0). Scatter-decode each word.
  {
    const float4* gy = (const float4*)(yt + (size_t)r0 * 26);
    for (int i = tid; i < RPB * 26 / 4; i += RPB) {
      const float4 v = gy[i];
      const int w = 4 * i;
#pragma unroll
      for (int q = 0; q < 4; ++q) {
        const float val = (q == 0) ? v.x : (q == 1) ? v.y : (q == 2) ? v.z : v.w;
        const int ww = w + q;
        const int r = ww / 26;          // const divisor -> mul_hi
        const int j = ww - r * 26;
        if (j < 4)            ((float*)s_loc)[r * 4 + j] = val;
        else if (j == 25)     s_pos[r] = val;
        else if (val > 0.5f)  s_lab[r] = j - 4;   // onehot -> label
      }
    }
  }
  __syncthreads();

  const int e = r0 + tid;
  const float4 lv = ((const float4*)lp)[e];     // loc_pred row: aligned float4
  const float4 tv = s_loc[tid];                 // ds_read_b128, conflict-free
  const float pos = s_pos[tid];
  const int lab = s_lab[tid];

  // smooth-L1 loc loss
  float ll;
  {
    const float d0 = tv.x - lv.x, d1 = tv.y - lv.y, d2 = tv.z - lv.z, d3 = tv.w - lv.w;
    const float a0 = fabsf(d0), a1 = fabsf(d1), a2 = fabsf(d2), a3 = fabsf(d3);
    ll  = (a0 < 1.f) ? 0.5f * d0 * d0 : a0 - 0.5f;
    ll += (a1 < 1.f) ? 0.5f * d1 * d1 : a1 - 0.5f;
    ll += (a2 < 1.f) ? 0.5f * d2 * d2 : a2 - 0.5f;
    ll += (a3 < 1.f) ? 0.5f * d3 * d3 : a3 - 0.5f;
  }

  // softmax stats from LDS (no register array -> no scratch)
  const float* c = s_cp + tid * NC;
  float mx = c[0];
#pragma unroll
  for (int j = 1; j < NC; ++j) mx = fmaxf(mx, c[j]);
  float ssum = 0.f, e0 = 0.f;
#pragma unroll
  for (int j = 0; j < NC; ++j) {
    const float ee = __expf(c[j] - mx);
    ssum += ee;
    if (j == 0) e0 = ee;
  }
  const float plogit = c[lab];                  // dynamic LDS index: fine
  const float cl = fminf(mx + __logf(ssum) - plogit, CLIP_MAX);
  const float mc = (1.f - pos) * ((ssum - e0) / ssum);

  MC[e] = mc;   // coalesced dword stores
  CL[e] = cl;

  // block reductions: pos-weighted sums + per-batch pos counts (<=2 batches/block)
  const int b0 = r0 / NBOX;
  const int bl = e / NBOX;
  float np0 = (bl == b0) ? pos : 0.f;
  float np1 = pos - np0;
  float pc = pos * cl, pw = pos * ll;
#pragma unroll
  for (int off = 32; off > 0; off >>= 1) {
    pc  += __shfl_down(pc, off);
    pw  += __shfl_down(pw, off);
    np0 += __shfl_down(np0, off);
    np1 += __shfl_down(np1, off);
  }
  const int wid = tid >> 6;
  if ((tid & 63) == 0) {
    sred[wid] = pc; sred[2 + wid] = pw; sred[4 + wid] = np0; sred[6 + wid] = np1;
  }
  __syncthreads();
  if (tid == 0) {
    const float a  = sred[0] + sred[1];
    const float b  = sred[2] + sred[3];
    const float n0 = sred[4] + sred[5];
    const float n1 = sred[6] + sred[7];
    if (a  != 0.f) atomicAdd(&ctl->pos_conf_sum, a);
    if (b  != 0.f) atomicAdd(&ctl->pos_loc_sum, b);
    if (n0 != 0.f) atomicAdd(&ctl->num_pos[b0], n0);
    if (n1 != 0.f) atomicAdd(&ctl->num_pos[b0 + 1], n1);   // only if straddling
  }
}

// ---------------------------------------------------------------------------
// Radix histograms (count + CL-sum). L1: top 10 bits, L2/L3: 11 bits each.
// MC/CL are 4.5 MB each -> L2/L3-resident.
// ---------------------------------------------------------------------------
template <int LEVEL>
__global__ __launch_bounds__(256) void k_hist(const float* __restrict__ MC,
                                              const float* __restrict__ CL,
                                              Ctl* __restrict__ ctl) {
  __shared__ unsigned int h[2048];
  __shared__ float hs[2048];
  for (int i = threadIdx.x; i < 2048; i += 256) { h[i] = 0u; hs[i] = 0.f; }
  __syncthreads();
  const unsigned int pfx = (LEVEL == 1) ? 0u : ctl->prefix;
  const float4* MC4 = (const float4*)MC;
  const float4* CL4 = (const float4*)CL;
  const int n4 = M / 4;
  const int stride = gridDim.x * 256;
  for (int i = blockIdx.x * 256 + threadIdx.x; i < n4; i += stride) {
    const float4 m = MC4[i];
    const float4 cv = CL4[i];
    const float mv[4]  = {m.x, m.y, m.z, m.w};
    const float cvv[4] = {cv.x, cv.y, cv.z, cv.w};
#pragma unroll
    for (int j = 0; j < 4; ++j) {
      const unsigned int bits = __float_as_uint(mv[j]);
      bool pass; unsigned int bin;
      if (LEVEL == 1)      { pass = true;                          bin = bits >> 22; }
      else if (LEVEL == 2) { pass = (bits >> 22) == (pfx >> 22);   bin = (bits >> 11) & 0x7FFu; }
      else                 { pass = (bits >> 11) == (pfx >> 11);   bin = bits & 0x7FFu; }
      if (pass) { atomicAdd(&h[bin], 1u); atomicAdd(&hs[bin], cvv[j]); }
    }
  }
  __syncthreads();
  for (int i = threadIdx.x; i < 2048; i += 256)
    if (h[i]) {
      atomicAdd(&ctl->hist[i], h[i]);
      atomicAdd(&ctl->hsum[i], hs[i]);
    }
}

// ---------------------------------------------------------------------------
// Radix-select scan over 2048 bins. LEVEL 1 computes k & denom; LEVEL 3 also
// emits the final scalar (k_combine folded in).
// ---------------------------------------------------------------------------
template <int LEVEL>
__global__ __launch_bounds__(1024) void k_scan(Ctl* __restrict__ ctl,
                                               float* __restrict__ out) {
  __shared__ unsigned int s[2048];
  __shared__ float sf[2048];
  __shared__ float red[16];
  __shared__ unsigned int kk;
  __shared__ int win;
  const int tid = threadIdx.x;

  if (LEVEL == 1) {
    const float np = (tid < BATCH) ? ctl->num_pos[tid] : 0.f;
    float nn  = fminf(3.0f * np, (float)NBOX - np);
    float hp  = (np > 0.f) ? 1.f : 0.f;
    float npc = (tid < BATCH) ? ((np != 0.f) ? np : 1.f) : 0.f;
#pragma unroll
    for (int off = 32; off > 0; off >>= 1) {
      nn += __shfl_down(nn, off);
      hp += __shfl_down(hp, off);
      npc += __shfl_down(npc, off);
    }
    __shared__ float rn[16], rh[16], rc[16];
    const int wid = tid >> 6;
    if ((tid & 63) == 0) { rn[wid] = nn; rh[wid] = hp; rc[wid] = npc; }
    __syncthreads();
    if (tid == 0) {
      float tn = 0.f, th = 0.f, tc = 0.f;
      for (int i = 0; i < 16; ++i) { tn += rn[i]; th += rh[i]; tc += rc[i]; }
      const float knb = (th > 0.f) ? tn : 100.0f;   // NEG_FOR_HARD
      const unsigned int k = (unsigned int)floorf(knb);
      ctl->denom = tc;
      ctl->k_rem = k;
      if (k == 0) ctl->done = 1;
      kk = k;
    }
  } else {
    if (tid == 0) kk = ctl->k_rem;
  }
  if (tid == 0) win = -1;

  s[tid]         = ctl->hist[tid];
  s[tid + 1024]  = ctl->hist[tid + 1024];
  sf[tid]        = ctl->hsum[tid];
  sf[tid + 1024] = ctl->hsum[tid + 1024];
  __syncthreads();

  const unsigned int krem = kk;   // uniform
  if (krem != 0) {
    // inclusive suffix scan (Hillis-Steele)
    for (int off = 1; off < 2048; off <<= 1) {
      const unsigned int v0 = (tid + off < 2048) ? s[tid + off] : 0u;
      const unsigned int v1 = (tid + 1024 + off < 2048) ? s[tid + 1024 + off] : 0u;
      __syncthreads();
      s[tid] += v0;
      s[tid + 1024] += v1;
      __syncthreads();
    }
    // unique bin b*: suffix[b*] >= k > suffix[b*+1]
#pragma unroll
    for (int t = 0; t < 2; ++t) {
      const int i = tid + t * 1024;
      const unsigned int si = s[i];
      const unsigned int sn = (i < 2047) ? s[i + 1] : 0u;
      if (si >= krem && sn < krem) win = i;
    }
    __syncthreads();
    const int b = win;   // uniform
    float acc = 0.f;
    if (b >= 0) {
      if (tid > b) acc += sf[tid];
      if (tid + 1024 > b) acc += sf[tid + 1024];
    }
#pragma unroll
    for (int off = 32; off > 0; off >>= 1) acc += __shfl_down(acc, off);
    const int wid = tid >> 6;
    if ((tid & 63) == 0) red[wid] = acc;
    __syncthreads();
    if (tid == 0 && b >= 0) {
      float tot = 0.f;
      for (int i = 0; i < 16; ++i) tot += red[i];
      ctl->s_gt += tot;   // single-block kernel, thread-0-private RMW
      const unsigned int above = (b < 2047) ? s[b + 1] : 0u;
      ctl->k_rem = krem - above;
      if (LEVEL == 1)      ctl->prefix = ((unsigned int)b) << 22;
      else if (LEVEL == 2) ctl->prefix |= ((unsigned int)b) << 11;
      else {
        ctl->prefix |= (unsigned int)b;
        ctl->n_eq = s[b] - above;
        ctl->s_eq = sf[b];
      }
    }
  }
  __syncthreads();
  ctl->hist[tid] = 0u;  ctl->hist[tid + 1024] = 0u;
  ctl->hsum[tid] = 0.f; ctl->hsum[tid + 1024] = 0.f;

  if (LEVEL == 3 && tid == 0) {   // fold in final combine (all fields tid0-local)
    float neg = ctl->s_gt;
    if (ctl->n_eq > 0) neg += ctl->s_eq * ((float)ctl->k_rem / (float)ctl->n_eq);
    out[0] = (ctl->pos_conf_sum + neg + ctl->pos_loc_sum) / ctl->denom;
  }
}

// ---------------------------------------------------------------------------
extern "C" void kernel_launch(void* const* d_in, const int* in_sizes, int n_in,
                              void* d_out, int out_size, void* d_ws, size_t ws_size,
                              hipStream_t stream) {
  const float* yt = (const float*)d_in[0];   // y_true    (B,N,26)
  const float* lp = (const float*)d_in[1];   // loc_pred  (B,N,4)
  const float* cp = (const float*)d_in[2];   // conf_pred (B,N,21)
  float* out = (float*)d_out;

  char* ws = (char*)d_ws;
  Ctl* ctl = (Ctl*)ws;                       // 16960 B
  float* MC = (float*)(ws + 20480);
  float* CL = MC + M;                        // ~8.96 MB total

  hipMemsetAsync(ctl, 0, sizeof(Ctl), stream);
  k_elem<<<NBLK, RPB, 0, stream>>>(yt, lp, cp, MC, CL, ctl);
  k_hist<1><<<1024, 256, 0, stream>>>(MC, CL, ctl);
  k_scan<1><<<1, 1024, 0, stream>>>(ctl, out);
  k_hist<2><<<1024, 256, 0, stream>>>(MC, CL, ctl);
  k_scan<2><<<1, 1024, 0, stream>>>(ctl, out);
  k_hist<3><<<1024, 256, 0, stream>>>(MC, CL, ctl);
  k_scan<3><<<1, 1024, 0, stream>>>(ctl, out);
}

// Round 5
// 289.678 us; speedup vs baseline: 1.6336x; 1.6336x over previous
//
#include <hip/hip_runtime.h>

#define BATCH 128
#define NBOX 8732
#define NC 21
#define M (BATCH * NBOX)            // 1,117,696
#define EBLK 2048                   // k_elem grid (16 blocks per batch)
#define SUBB 16
#define CHUNK 546                   // rows per block; last block of batch: 542
#define NREP 32                     // histogram replicas (contention /64)
#define CLIP_MAX 16.118095651f      // -log(1e-7)

struct Ctl {
  float pos_conf_sum, pos_loc_sum, s_gt, denom;
  unsigned int k_rem, d1, d2, pad;
};

// ws byte offsets
#define OFF_NPP 1024
#define OFF_PCP (OFF_NPP + 8192)
#define OFF_PLP (OFF_PCP + 8192)
#define OFF_REP 32768
#define REPSZ   (NREP * 2048 * 4)         // 256 KB per array
#define OFF_MC  (OFF_REP + 6 * REPSZ)     // 1,605,632
#define OFF_CL  (OFF_MC + M * 4)          // total ~10.5 MB
#define ZERO_BYTES OFF_MC

// 33-bit linear fixed-point key over [0,1): monotone in mc, injective for mc>2^-10
__device__ __forceinline__ unsigned long long mckey(float mc) {
  unsigned long long K = (unsigned long long)((double)mc * 8589934592.0);  // *2^33
  return (K > 0x1FFFFFFFFull) ? 0x1FFFFFFFFull : K;
}

// ---------------------------------------------------------------------------
// Fused elementwise + L1 histogram. Direct per-thread loads (no staging, no
// barriers in hot loop). Batch-aligned blocks; zero global atomics.
// ---------------------------------------------------------------------------
__global__ __launch_bounds__(256) void k_elem(
    const float* __restrict__ yt, const float* __restrict__ lp,
    const float* __restrict__ cp, float* __restrict__ MC,
    float* __restrict__ CL, float* __restrict__ np_part,
    float* __restrict__ pc_part, float* __restrict__ pl_part,
    unsigned int* __restrict__ rep1c, float* __restrict__ rep1s) {
  __shared__ unsigned int hc[2048];
  __shared__ float hs[2048];
  __shared__ float sred[12];
  const int tid = threadIdx.x;
  const int bid = blockIdx.x;
  for (int i = tid; i < 2048; i += 256) { hc[i] = 0u; hs[i] = 0.f; }
  __syncthreads();

  const int batch = bid >> 4;
  const int sub = bid & 15;
  const int base = batch * NBOX + sub * CHUNK;
  const int cnt = (sub == SUBB - 1) ? (NBOX - (SUBB - 1) * CHUNK) : CHUNK;

  float tpc = 0.f, tpl = 0.f, tnp = 0.f;
  for (int i = tid; i < cnt; i += 256) {
    const int e = base + i;
    // conf row: 21 scalar dwords (rows 84B, only 4B-aligned); lines fully consumed
    const float* crow = cp + (size_t)e * NC;
    float cv[NC];
#pragma unroll
    for (int j = 0; j < NC; ++j) cv[j] = crow[j];
    // y_true row: 26 floats = 13 aligned float2 (stride 104B, 8B-aligned)
    const float2* y2 = (const float2*)(yt + (size_t)e * 26);
    float2 yw[13];
#pragma unroll
    for (int j = 0; j < 13; ++j) yw[j] = y2[j];
    const float4 lv = ((const float4*)lp)[e];   // 16B-aligned
    const float pos = yw[12].y;

    // smooth-L1 loc loss
    const float d0 = yw[0].x - lv.x, d1 = yw[0].y - lv.y;
    const float d2 = yw[1].x - lv.z, d3 = yw[1].y - lv.w;
    const float a0 = fabsf(d0), a1 = fabsf(d1), a2 = fabsf(d2), a3 = fabsf(d3);
    float ll = ((a0 < 1.f) ? 0.5f * d0 * d0 : a0 - 0.5f)
             + ((a1 < 1.f) ? 0.5f * d1 * d1 : a1 - 0.5f)
             + ((a2 < 1.f) ? 0.5f * d2 * d2 : a2 - 0.5f)
             + ((a3 < 1.f) ? 0.5f * d3 * d3 : a3 - 0.5f);

    // softmax stats (all static indexing; no scratch)
    float mx = cv[0];
#pragma unroll
    for (int j = 1; j < NC; ++j) mx = fmaxf(mx, cv[j]);
    float plogit = 0.f;           // onehot dot logits: exact label-logit select
#pragma unroll
    for (int j = 0; j < NC; ++j) {
      const int w = 4 + j;
      const float oh = (w & 1) ? yw[w >> 1].y : yw[w >> 1].x;
      plogit = fmaf(oh, cv[j], plogit);
    }
    float ssum = 0.f, e0 = 0.f;
#pragma unroll
    for (int j = 0; j < NC; ++j) {
      const float ee = __expf(cv[j] - mx);
      ssum += ee;
      if (j == 0) e0 = ee;
    }
    const float cl = fminf(mx + __logf(ssum) - plogit, CLIP_MAX);
    const float mc = (1.f - pos) * ((ssum - e0) / ssum);

    MC[e] = mc;
    CL[e] = cl;
    const unsigned int b1 = (unsigned int)(mckey(mc) >> 22);  // top 11 bits
    atomicAdd(&hc[b1], 1u);
    atomicAdd(&hs[b1], cl);
    tpc += pos * cl;
    tpl += pos * ll;
    tnp += pos;
  }

  // block-reduce the three scalars -> per-block partial arrays (no global atomics)
#pragma unroll
  for (int off = 32; off > 0; off >>= 1) {
    tpc += __shfl_down(tpc, off);
    tpl += __shfl_down(tpl, off);
    tnp += __shfl_down(tnp, off);
  }
  if ((tid & 63) == 0) {
    const int w = tid >> 6;
    sred[w] = tpc; sred[4 + w] = tpl; sred[8 + w] = tnp;
  }
  __syncthreads();
  if (tid == 0) {
    pc_part[bid] = sred[0] + sred[1] + sred[2] + sred[3];
    pl_part[bid] = sred[4] + sred[5] + sred[6] + sred[7];
    np_part[bid] = sred[8] + sred[9] + sred[10] + sred[11];
  }
  // flush LDS hist into replica (bid & 31): same-address chains <= 64
  unsigned int* rc = rep1c + (bid & (NREP - 1)) * 2048;
  float* rs = rep1s + (bid & (NREP - 1)) * 2048;
  for (int i = tid; i < 2048; i += 256)
    if (hc[i]) { atomicAdd(&rc[i], hc[i]); atomicAdd(&rs[i], hs[i]); }
}

// ---------------------------------------------------------------------------
// Refinement histograms for radix levels 2/3 (filter by prefix digits).
// ---------------------------------------------------------------------------
template <int LEVEL>
__global__ __launch_bounds__(256) void k_hist(
    const float* __restrict__ MC, const float* __restrict__ CL,
    unsigned int* __restrict__ repc, float* __restrict__ reps,
    const Ctl* __restrict__ ctl) {
  __shared__ unsigned int hc[2048];
  __shared__ float hs[2048];
  for (int i = threadIdx.x; i < 2048; i += 256) { hc[i] = 0u; hs[i] = 0.f; }
  __syncthreads();
  const unsigned int dd = (LEVEL == 2) ? ctl->d1 : ((ctl->d1 << 11) | ctl->d2);
  const float4* M4 = (const float4*)MC;
  const int n4 = M / 4;
  const int stride = gridDim.x * 256;
  for (int i = blockIdx.x * 256 + threadIdx.x; i < n4; i += stride) {
    const float4 m = M4[i];
    const float mv[4] = {m.x, m.y, m.z, m.w};
#pragma unroll
    for (int q = 0; q < 4; ++q) {
      const unsigned long long K = mckey(mv[q]);
      bool match; unsigned int bin;
      if (LEVEL == 2) { match = (unsigned int)(K >> 22) == dd; bin = (unsigned int)(K >> 11) & 2047u; }
      else            { match = (unsigned int)(K >> 11) == dd; bin = (unsigned int)K & 2047u; }
      if (match) {            // rare (~1/2048 of elements) -> cheap divergent load
        const float cl = CL[4 * i + q];
        atomicAdd(&hc[bin], 1u);
        atomicAdd(&hs[bin], cl);
      }
    }
  }
  __syncthreads();
  unsigned int* rc = repc + (blockIdx.x & (NREP - 1)) * 2048;
  float* rs = reps + (blockIdx.x & (NREP - 1)) * 2048;
  for (int i = threadIdx.x; i < 2048; i += 256)
    if (hc[i]) { atomicAdd(&rc[i], hc[i]); atomicAdd(&rs[i], hs[i]); }
}

// ---------------------------------------------------------------------------
// Scan: reduce replicas, suffix-scan counts, pick k-th-largest bin, accumulate
// CL-sum of fully-selected bins. L1 computes k/denom/pos-sums; L3 emits output.
// ---------------------------------------------------------------------------
template <int LEVEL>
__global__ __launch_bounds__(1024) void k_scan(
    const unsigned int* __restrict__ repc, const float* __restrict__ reps,
    const float* __restrict__ np_part, const float* __restrict__ pc_part,
    const float* __restrict__ pl_part, Ctl* __restrict__ ctl,
    float* __restrict__ out) {
  __shared__ unsigned int s[2048];
  __shared__ float sf[2048];
  __shared__ float red[16], rn[16], rh[16], rc[16], ra[16], rb[16];
  __shared__ unsigned int kk;
  __shared__ int win;
  const int tid = threadIdx.x;

  // reduce 32 replicas (coalesced sweeps)
  unsigned int c0 = 0, c1 = 0;
  float f0 = 0.f, f1 = 0.f;
  for (int r = 0; r < NREP; ++r) {
    c0 += repc[r * 2048 + tid];
    c1 += repc[r * 2048 + tid + 1024];
    f0 += reps[r * 2048 + tid];
    f1 += reps[r * 2048 + tid + 1024];
  }
  s[tid] = c0; s[tid + 1024] = c1;
  sf[tid] = f0; sf[tid + 1024] = f1;

  if (LEVEL == 1) {
    float np = 0.f;
    if (tid < BATCH)
      for (int j = 0; j < SUBB; ++j) np += np_part[tid * SUBB + j];
    float nn  = fminf(3.0f * np, (float)NBOX - np);   // 0 for tid>=BATCH
    float hp  = (np > 0.f) ? 1.f : 0.f;
    float npc = (tid < BATCH) ? ((np != 0.f) ? np : 1.f) : 0.f;
    float a = pc_part[tid] + pc_part[tid + 1024];
    float b = pl_part[tid] + pl_part[tid + 1024];
#pragma unroll
    for (int off = 32; off > 0; off >>= 1) {
      nn += __shfl_down(nn, off);   hp += __shfl_down(hp, off);
      npc += __shfl_down(npc, off); a += __shfl_down(a, off);
      b += __shfl_down(b, off);
    }
    const int w = tid >> 6;
    if ((tid & 63) == 0) { rn[w] = nn; rh[w] = hp; rc[w] = npc; ra[w] = a; rb[w] = b; }
    __syncthreads();
    if (tid == 0) {
      float tn = 0.f, th = 0.f, tc = 0.f, ta = 0.f, tb = 0.f;
      for (int i = 0; i < 16; ++i) { tn += rn[i]; th += rh[i]; tc += rc[i]; ta += ra[i]; tb += rb[i]; }
      ctl->denom = tc;
      ctl->pos_conf_sum = ta;
      ctl->pos_loc_sum = tb;
      kk = (unsigned int)floorf((th > 0.f) ? tn : 100.0f);   // NEG_FOR_HARD
    }
  } else {
    if (tid == 0) kk = ctl->k_rem;
  }
  if (tid == 0) win = -1;
  __syncthreads();

  const unsigned int krem = kk;   // uniform
  if (krem != 0) {
    // inclusive suffix scan (Hillis-Steele), barriered read/write phases
    for (int off = 1; off < 2048; off <<= 1) {
      const unsigned int v0 = (tid + off < 2048) ? s[tid + off] : 0u;
      const unsigned int v1 = (tid + 1024 + off < 2048) ? s[tid + 1024 + off] : 0u;
      __syncthreads();
      s[tid] += v0;
      s[tid + 1024] += v1;
      __syncthreads();
    }
    // unique bin b*: suffix[b*] >= k > suffix[b*+1]
#pragma unroll
    for (int t = 0; t < 2; ++t) {
      const int i = tid + t * 1024;
      const unsigned int si = s[i];
      const unsigned int sn = (i < 2047) ? s[i + 1] : 0u;
      if (si >= krem && sn < krem) win = i;
    }
    __syncthreads();
    const int b = win;   // uniform
    float acc = 0.f;     // CL sum of fully-selected bins (strictly above b*)
    if (b >= 0) {
      if (tid > b) acc += sf[tid];
      if (tid + 1024 > b) acc += sf[tid + 1024];
    }
#pragma unroll
    for (int off = 32; off > 0; off >>= 1) acc += __shfl_down(acc, off);
    if ((tid & 63) == 0) red[tid >> 6] = acc;
    __syncthreads();
    if (tid == 0 && b >= 0) {
      float tot = 0.f;
      for (int i = 0; i < 16; ++i) tot += red[i];
      const unsigned int above = (b < 2047) ? s[b + 1] : 0u;
      const unsigned int krem2 = krem - above;
      if (LEVEL < 3) {
        ctl->s_gt += tot;
        ctl->k_rem = krem2;
        if (LEVEL == 1) ctl->d1 = (unsigned int)b;
        else            ctl->d2 = (unsigned int)b;
      } else {
        const unsigned int neq = s[b] - above;   // bit-exact ties
        const float tie = (neq > 0) ? sf[b] * ((float)krem2 / (float)neq) : 0.f;
        const float neg = ctl->s_gt + tot + tie;
        out[0] = (ctl->pos_conf_sum + neg + ctl->pos_loc_sum) / ctl->denom;
      }
    }
  } else if (LEVEL == 3 && tid == 0) {   // defensive: k==0 cannot occur
    out[0] = (ctl->pos_conf_sum + ctl->s_gt + ctl->pos_loc_sum) / ctl->denom;
  }
}

// ---------------------------------------------------------------------------
extern "C" void kernel_launch(void* const* d_in, const int* in_sizes, int n_in,
                              void* d_out, int out_size, void* d_ws, size_t ws_size,
                              hipStream_t stream) {
  const float* yt = (const float*)d_in[0];   // y_true    (B,N,26)
  const float* lp = (const float*)d_in[1];   // loc_pred  (B,N,4)
  const float* cp = (const float*)d_in[2];   // conf_pred (B,N,21)
  float* out = (float*)d_out;

  char* ws = (char*)d_ws;
  Ctl* ctl = (Ctl*)ws;
  float* np_part = (float*)(ws + OFF_NPP);
  float* pc_part = (float*)(ws + OFF_PCP);
  float* pl_part = (float*)(ws + OFF_PLP);
  unsigned int* rep1c = (unsigned int*)(ws + OFF_REP);
  float*        rep1s = (float*)(ws + OFF_REP + 1 * REPSZ);
  unsigned int* rep2c = (unsigned int*)(ws + OFF_REP + 2 * REPSZ);
  float*        rep2s = (float*)(ws + OFF_REP + 3 * REPSZ);
  unsigned int* rep3c = (unsigned int*)(ws + OFF_REP + 4 * REPSZ);
  float*        rep3s = (float*)(ws + OFF_REP + 5 * REPSZ);
  float* MC = (float*)(ws + OFF_MC);
  float* CL = (float*)(ws + OFF_CL);

  hipMemsetAsync(ws, 0, ZERO_BYTES, stream);   // ctl + partials + all replicas
  k_elem<<<EBLK, 256, 0, stream>>>(yt, lp, cp, MC, CL, np_part, pc_part, pl_part,
                                   rep1c, rep1s);
  k_scan<1><<<1, 1024, 0, stream>>>(rep1c, rep1s, np_part, pc_part, pl_part, ctl, out);
  k_hist<2><<<1024, 256, 0, stream>>>(MC, CL, rep2c, rep2s, ctl);
  k_scan<2><<<1, 1024, 0, stream>>>(rep2c, rep2s, np_part, pc_part, pl_part, ctl, out);
  k_hist<3><<<1024, 256, 0, stream>>>(MC, CL, rep3c, rep3s, ctl);
  k_scan<3><<<1, 1024, 0, stream>>>(rep3c, rep3s, np_part, pc_part, pl_part, ctl, out);
}